// Round 7
// baseline (146.449 us; speedup 1.0000x reference)
//
#include <hip/hip_runtime.h>
#include <math.h>

#define B_DIM 16
#define C_DIM 256
#define NV    40962
#define K_NEI 7
#define NPAIR (NV / 2)   // 20481
#define GRP   10241      // groups of 4 consecutive n per b (last group overlaps)

typedef float v2f __attribute__((ext_vector_type(2)));

// Kernel 1: channel-wise mean+max. Thread = (b, group of 4 consecutive n) via
// two float2 nt-loads (NV%4==2 -> float4 would be 8B-misaligned on odd c).
// Block = 512 threads -> per c-iteration each block reads one contiguous 8KB
// span (vs 4KB in R6, 2KB in R5): fewer, larger instantaneous DRAM chunks.
// 321 blocks x 8 waves = 2568 waves (~10/CU) all co-resident.
__global__ __launch_bounds__(512) void pool_kernel(const float* __restrict__ x,
                                                   float4* __restrict__ pool) {
    int t = blockIdx.x * 512 + threadIdx.x;
    if (t >= B_DIM * GRP) return;
    int b = t / GRP;
    int r = t - b * GRP;
    int n0 = 4 * r; if (n0 > NV - 4) n0 = NV - 4;   // tail overlaps; writes bit-identical

    const float* xb = x + (size_t)b * C_DIM * NV + n0;

    float s0 = 0.f, s1 = 0.f, s2 = 0.f, s3 = 0.f;
    float m0 = -INFINITY, m1 = -INFINITY, m2 = -INFINITY, m3 = -INFINITY;
    #pragma unroll 16
    for (int c = 0; c < C_DIM; ++c) {
        const float* p = xb + (size_t)c * NV;
        v2f va = __builtin_nontemporal_load(reinterpret_cast<const v2f*>(p));
        v2f vb = __builtin_nontemporal_load(reinterpret_cast<const v2f*>(p + 2));
        s0 += va.x; s1 += va.y; s2 += vb.x; s3 += vb.y;
        m0 = fmaxf(m0, va.x); m1 = fmaxf(m1, va.y);
        m2 = fmaxf(m2, vb.x); m3 = fmaxf(m3, vb.y);
    }
    const float inv = 1.0f / (float)C_DIM;
    size_t f4 = ((size_t)b * NV + n0) >> 1;          // [b][n] float2 -> float4 index
    pool[f4]     = make_float4(s0 * inv, m0, s1 * inv, m1);
    pool[f4 + 1] = make_float4(s2 * inv, m2, s3 * inv, m3);
}

// Kernel 2 (proven): transpose pool [b][n] -> poolT [n][b].
__global__ void transpose_kernel(const float2* __restrict__ pool,
                                 float2* __restrict__ poolT) {
    __shared__ float2 tile[64][17];
    int n0 = blockIdx.x * 64;
    int i  = threadIdx.x & 63;
    int bq = threadIdx.x >> 6;        // 0..3
    #pragma unroll
    for (int p = 0; p < 4; ++p) {
        int b = p * 4 + bq;
        if (n0 + i < NV)
            tile[i][b] = pool[(size_t)b * NV + n0 + i];
    }
    __syncthreads();
    int valid = NV - n0; if (valid > 64) valid = 64;
    int nf4 = valid * 8;
    float4* dst = reinterpret_cast<float4*>(poolT + (size_t)n0 * 16);
    for (int e = threadIdx.x; e < nf4; e += 256) {
        int e2 = e * 2;
        int n  = e2 >> 4;
        int b  = e2 & 15;
        float2 a0 = tile[n][b];
        float2 a1 = tile[n][b + 1];
        dst[e] = make_float4(a0.x, a0.y, a1.x, a1.y);
    }
}

// Kernel 3 (proven): 4 threads per vertex, 4 b each; full-line gathers.
__global__ void att4_kernel(const float2* __restrict__ poolT,
                            const int* __restrict__ idx,
                            const float* __restrict__ W,
                            const float* __restrict__ bias,
                            float* __restrict__ out) {
    int tid = threadIdx.x;
    int n   = blockIdx.x * 64 + (tid >> 2);
    int bq  = tid & 3;
    if (n >= NV) return;

    float w[2 * K_NEI];
    #pragma unroll
    for (int i = 0; i < 2 * K_NEI; ++i) w[i] = W[i];
    float bb = bias[0];

    float acc[4];
    #pragma unroll
    for (int r = 0; r < 4; ++r) acc[r] = bb;

    #pragma unroll
    for (int k = 0; k < K_NEI; ++k) {
        int j = idx[n * K_NEI + k];
        const float4* L = reinterpret_cast<const float4*>(poolT + (size_t)j * 16 + bq * 4);
        float4 v0 = L[0];
        float4 v1 = L[1];
        acc[0] = fmaf(w[2 * k + 1], v0.y, fmaf(w[2 * k], v0.x, acc[0]));
        acc[1] = fmaf(w[2 * k + 1], v0.w, fmaf(w[2 * k], v0.z, acc[1]));
        acc[2] = fmaf(w[2 * k + 1], v1.y, fmaf(w[2 * k], v1.x, acc[2]));
        acc[3] = fmaf(w[2 * k + 1], v1.w, fmaf(w[2 * k], v1.z, acc[3]));
    }
    #pragma unroll
    for (int r = 0; r < 4; ++r)
        out[(size_t)(bq * 4 + r) * NV + n] = 1.0f / (1.0f + expf(-acc[r]));
}

extern "C" void kernel_launch(void* const* d_in, const int* in_sizes, int n_in,
                              void* d_out, int out_size, void* d_ws, size_t ws_size,
                              hipStream_t stream) {
    const float* x     = (const float*)d_in[0];
    const int*   neigh = (const int*)  d_in[1];
    const float* W     = (const float*)d_in[2];
    const float* bias  = (const float*)d_in[3];
    float*       out   = (float*)d_out;

    const size_t POOL_BYTES = (size_t)B_DIM * NV * sizeof(float2); // 5.24 MB

    float4* pool4 = (float4*)d_ws;                        // [b][n] staging
    float2* poolT = (float2*)((char*)d_ws + POOL_BYTES);  // [n][b]

    int t1 = B_DIM * GRP;                 // 163,856
    pool_kernel<<<(t1 + 511) / 512, 512, 0, stream>>>(x, pool4);

    int ntile = (NV + 63) / 64;           // 641
    transpose_kernel<<<ntile, 256, 0, stream>>>((const float2*)d_ws, poolT);
    att4_kernel<<<ntile, 256, 0, stream>>>(poolT, neigh, W, bias, out);
}

// Round 8
// 131.304 us; speedup vs baseline: 1.1153x; 1.1153x over previous
//
#include <hip/hip_runtime.h>
#include <math.h>

#define B_DIM 16
#define C_DIM 256
#define NV    40962
#define K_NEI 7
#define GRP   10240      // full 4-n groups per b; n 40960..40961 handled by tail block
#define MAIN_BLOCKS 2560 // 16*GRP/64 — exactly 10 blocks per CU, 320 per XCD

typedef float v2f __attribute__((ext_vector_type(2)));

// Kernel 1: channel-wise mean+max. 64-thread blocks, 1 thread = (b, 4 consecutive n)
// via two nontemporal float2 loads (same wave pattern as the proven R6 kernel:
// 1KB contiguous per wave-instant). Grid = 2560 uniform blocks (exactly 10/CU,
// no ceil imbalance) + 1 tail block for the 32 leftover (b,n) columns.
__global__ __launch_bounds__(64) void pool_kernel(const float* __restrict__ x,
                                                  float4* __restrict__ pool) {
    if (blockIdx.x < MAIN_BLOCKS) {
        int t  = blockIdx.x * 64 + threadIdx.x;     // < 163,840 exactly
        int b  = t / GRP;
        int r  = t - b * GRP;
        int n0 = 4 * r;                             // 0..40956

        const float* xb = x + (size_t)b * C_DIM * NV + n0;

        float s0 = 0.f, s1 = 0.f, s2 = 0.f, s3 = 0.f;
        float m0 = -INFINITY, m1 = -INFINITY, m2 = -INFINITY, m3 = -INFINITY;
        #pragma unroll 16
        for (int c = 0; c < C_DIM; ++c) {
            const float* p = xb + (size_t)c * NV;
            v2f va = __builtin_nontemporal_load(reinterpret_cast<const v2f*>(p));
            v2f vb = __builtin_nontemporal_load(reinterpret_cast<const v2f*>(p + 2));
            s0 += va.x; s1 += va.y; s2 += vb.x; s3 += vb.y;
            m0 = fmaxf(m0, va.x); m1 = fmaxf(m1, va.y);
            m2 = fmaxf(m2, vb.x); m3 = fmaxf(m3, vb.y);
        }
        const float inv = 1.0f / (float)C_DIM;
        size_t f4 = ((size_t)b * NV + n0) >> 1;     // [b][n] float2 -> float4 index
        pool[f4]     = make_float4(s0 * inv, m0, s1 * inv, m1);
        pool[f4 + 1] = make_float4(s2 * inv, m2, s3 * inv, m3);
    } else {
        // Tail block: 32 columns (b in 0..15, n in {40960,40961}) x 2 c-halves.
        __shared__ float2 part[64];                 // (sum, max) partials
        int tid  = threadIdx.x;
        int col  = tid >> 1;                        // 0..31
        int half = tid & 1;                         // 0..1
        int b    = col >> 1;
        int n    = 40960 + (col & 1);

        const float* xb = x + (size_t)b * C_DIM * NV + n;
        float s = 0.f, m = -INFINITY;
        #pragma unroll 8
        for (int c = half * 128; c < half * 128 + 128; ++c) {
            float v = xb[(size_t)c * NV];
            s += v; m = fmaxf(m, v);
        }
        part[tid] = make_float2(s, m);
        __syncthreads();
        if (half == 0) {
            float2 a = part[tid], bb2 = part[tid + 1];
            float2* poolf2 = reinterpret_cast<float2*>(pool);
            poolf2[(size_t)b * NV + n] =
                make_float2((a.x + bb2.x) * (1.0f / (float)C_DIM), fmaxf(a.y, bb2.y));
        }
    }
}

// Kernel 2 (proven): transpose pool [b][n] -> poolT [n][b].
__global__ void transpose_kernel(const float2* __restrict__ pool,
                                 float2* __restrict__ poolT) {
    __shared__ float2 tile[64][17];
    int n0 = blockIdx.x * 64;
    int i  = threadIdx.x & 63;
    int bq = threadIdx.x >> 6;        // 0..3
    #pragma unroll
    for (int p = 0; p < 4; ++p) {
        int b = p * 4 + bq;
        if (n0 + i < NV)
            tile[i][b] = pool[(size_t)b * NV + n0 + i];
    }
    __syncthreads();
    int valid = NV - n0; if (valid > 64) valid = 64;
    int nf4 = valid * 8;
    float4* dst = reinterpret_cast<float4*>(poolT + (size_t)n0 * 16);
    for (int e = threadIdx.x; e < nf4; e += 256) {
        int e2 = e * 2;
        int n  = e2 >> 4;
        int b  = e2 & 15;
        float2 a0 = tile[n][b];
        float2 a1 = tile[n][b + 1];
        dst[e] = make_float4(a0.x, a0.y, a1.x, a1.y);
    }
}

// Kernel 3 (proven): 4 threads per vertex, 4 b each; full-line gathers.
__global__ void att4_kernel(const float2* __restrict__ poolT,
                            const int* __restrict__ idx,
                            const float* __restrict__ W,
                            const float* __restrict__ bias,
                            float* __restrict__ out) {
    int tid = threadIdx.x;
    int n   = blockIdx.x * 64 + (tid >> 2);
    int bq  = tid & 3;
    if (n >= NV) return;

    float w[2 * K_NEI];
    #pragma unroll
    for (int i = 0; i < 2 * K_NEI; ++i) w[i] = W[i];
    float bb = bias[0];

    float acc[4];
    #pragma unroll
    for (int r = 0; r < 4; ++r) acc[r] = bb;

    #pragma unroll
    for (int k = 0; k < K_NEI; ++k) {
        int j = idx[n * K_NEI + k];
        const float4* L = reinterpret_cast<const float4*>(poolT + (size_t)j * 16 + bq * 4);
        float4 v0 = L[0];
        float4 v1 = L[1];
        acc[0] = fmaf(w[2 * k + 1], v0.y, fmaf(w[2 * k], v0.x, acc[0]));
        acc[1] = fmaf(w[2 * k + 1], v0.w, fmaf(w[2 * k], v0.z, acc[1]));
        acc[2] = fmaf(w[2 * k + 1], v1.y, fmaf(w[2 * k], v1.x, acc[2]));
        acc[3] = fmaf(w[2 * k + 1], v1.w, fmaf(w[2 * k], v1.z, acc[3]));
    }
    #pragma unroll
    for (int r = 0; r < 4; ++r)
        out[(size_t)(bq * 4 + r) * NV + n] = 1.0f / (1.0f + expf(-acc[r]));
}

extern "C" void kernel_launch(void* const* d_in, const int* in_sizes, int n_in,
                              void* d_out, int out_size, void* d_ws, size_t ws_size,
                              hipStream_t stream) {
    const float* x     = (const float*)d_in[0];
    const int*   neigh = (const int*)  d_in[1];
    const float* W     = (const float*)d_in[2];
    const float* bias  = (const float*)d_in[3];
    float*       out   = (float*)d_out;

    const size_t POOL_BYTES = (size_t)B_DIM * NV * sizeof(float2); // 5.24 MB

    float4* pool4 = (float4*)d_ws;                        // [b][n] staging
    float2* poolT = (float2*)((char*)d_ws + POOL_BYTES);  // [n][b]

    pool_kernel<<<MAIN_BLOCKS + 1, 64, 0, stream>>>(x, pool4);

    int ntile = (NV + 63) / 64;           // 641
    transpose_kernel<<<ntile, 256, 0, stream>>>((const float2*)d_ws, poolT);
    att4_kernel<<<ntile, 256, 0, stream>>>(poolT, neigh, W, bias, out);
}